// Round 5
// baseline (370.211 us; speedup 1.0000x reference)
//
#include <hip/hip_runtime.h>
#include <cstdint>
#include <cstddef>

#define NPIX 9216          // 96*96
#define NB 2
#define NC 256
#define RC 64
#define TK 16
#define NROWS (NB * NPIX)  // 18432
#define CT 96              // cols per LDS tile
#define SST 72             // LDS col stride in ushorts (144B: 2-way-free reads)
#define NQ 16              // col splits
#define ECOLS 576          // cols per split
#define NTE 6              // tiles per split
#define NCHK 128           // chunk maxima per row (72 cols each)
#define MAXC 128           // compact candidate slots per row
#define MARGIN 0.008f      // 2*e, e <= 2*2^-9 * ||a||*||b|| = 3.9e-3

typedef unsigned short ushort_t;
typedef unsigned int uint_t;
typedef __bf16 bf16x8 __attribute__((ext_vector_type(8)));
typedef float f32x4 __attribute__((ext_vector_type(4)));

__device__ __forceinline__ uint_t f2bf(float x) {
  uint_t u = __float_as_uint(x);
  return (u + 0x7FFFu + ((u >> 16) & 1u)) >> 16;
}

// monotone float->uint map (bigger float => bigger uint)
__device__ __forceinline__ uint_t ordu(float v) {
  uint_t u = __float_as_uint(v);
  return (u & 0x80000000u) ? ~u : (u | 0x80000000u);
}

// ---------------- K1: 1x1 conv reduce, c-split partials ----------------
// grid: 72 pixgroups x 2 rh x 4 cq = 576. feat4 layout [rh*4+cq][NROWS][32]
__global__ __launch_bounds__(256) void k_reduce(
    const float* __restrict__ x, const float* __restrict__ wr,
    float* __restrict__ feat4) {
  __shared__ float wl[64 * 32];  // 8 KB: [c_local][r_local]
  const int bi = blockIdx.x;
  const int pg = bi >> 3, rh = (bi >> 2) & 1, cq = bi & 3;
  const int tid = threadIdx.x;
  {
    const int cl = tid >> 2, rg = (tid & 3) * 8;
#pragma unroll
    for (int i = 0; i < 8; ++i)
      wl[cl * 32 + rg + i] = wr[(size_t)(rh * 32 + rg + i) * NC + cq * 64 + cl];
  }
  __syncthreads();

  const int p = pg * 256 + tid;
  const int b = p >= NPIX;
  const int n = p - b * NPIX;
  const float* xp = x + (size_t)b * NC * NPIX + (size_t)cq * 64 * NPIX + n;

  float4 acc[8];
#pragma unroll
  for (int i = 0; i < 8; ++i) acc[i] = make_float4(0.f, 0.f, 0.f, 0.f);

  for (int c = 0; c < 64; ++c) {
    const float xv = xp[(size_t)c * NPIX];           // coalesced
    const float4* w4 = (const float4*)(wl + c * 32); // broadcast
#pragma unroll
    for (int i = 0; i < 8; ++i) {
      float4 w = w4[i];
      acc[i].x += w.x * xv; acc[i].y += w.y * xv;
      acc[i].z += w.z * xv; acc[i].w += w.w * xv;
    }
  }
  float4* o = (float4*)(feat4 + (((size_t)(rh * 4 + cq)) * NROWS + p) * 32);
#pragma unroll
  for (int i = 0; i < 8; ++i) o[i] = acc[i];  // 128B/lane contiguous
}

// ---------------- K1b: sum partials + normalize + bf16 hi ----------------
__global__ __launch_bounds__(256) void k_normsplit(
    const float* __restrict__ feat4, float* __restrict__ nf,
    ushort_t* __restrict__ hi) {
  const int t = blockIdx.x * 256 + threadIdx.x;
  const int p = t >> 2, q = t & 3;  // 4 lanes per pixel, lane q owns r [q*16,q*16+16)
  const int rh = q >> 1, so = (q & 1) * 16;
  float4 v[4];
#pragma unroll
  for (int i = 0; i < 4; ++i) v[i] = make_float4(0.f, 0.f, 0.f, 0.f);
#pragma unroll
  for (int pt = 0; pt < 4; ++pt) {
    const float4* fp = (const float4*)(feat4 + (((size_t)(rh * 4 + pt)) * NROWS + p) * 32 + so);
#pragma unroll
    for (int i = 0; i < 4; ++i) {
      float4 a = fp[i];
      v[i].x += a.x; v[i].y += a.y; v[i].z += a.z; v[i].w += a.w;
    }
  }
  float ssq = 0.f;
#pragma unroll
  for (int i = 0; i < 4; ++i)
    ssq += v[i].x * v[i].x + v[i].y * v[i].y + v[i].z * v[i].z + v[i].w * v[i].w;
  ssq += __shfl_xor(ssq, 1);
  ssq += __shfl_xor(ssq, 2);
  const float inv = 1.f / fmaxf(sqrtf(ssq), 1e-12f);

  float s[16];
#pragma unroll
  for (int i = 0; i < 4; ++i) {
    s[i * 4 + 0] = v[i].x * inv; s[i * 4 + 1] = v[i].y * inv;
    s[i * 4 + 2] = v[i].z * inv; s[i * 4 + 3] = v[i].w * inv;
  }
  float4* no = (float4*)(nf + (size_t)p * RC + q * 16);
#pragma unroll
  for (int i = 0; i < 4; ++i)
    no[i] = make_float4(s[i * 4], s[i * 4 + 1], s[i * 4 + 2], s[i * 4 + 3]);

  uint_t hs[16];
#pragma unroll
  for (int i = 0; i < 16; ++i) hs[i] = f2bf(s[i]);
  uint4* ho = (uint4*)(hi + (size_t)p * RC + q * 16);
#pragma unroll
  for (int h = 0; h < 2; ++h)
    ho[h] = make_uint4(hs[h*8+0] | (hs[h*8+1] << 16), hs[h*8+2] | (hs[h*8+3] << 16),
                       hs[h*8+4] | (hs[h*8+5] << 16), hs[h*8+6] | (hs[h*8+7] << 16));
}

// ---------------- K2a: pass A — hi sims, per-lane chunk maxima ----------------
// grid: 144 rowblocks(128 rows) x 16 col-splits = 2304; double-buffered staging
__global__ __launch_bounds__(256) void k_sim_max(
    const ushort_t* __restrict__ nf_hi, float* __restrict__ tmax) {
  __shared__ ushort_t sh[CT * SST];  // 13.5 KB
  const int rb = blockIdx.x >> 4, q = blockIdx.x & 15;
  const int tid = threadIdx.x, wave = tid >> 6, lane = tid & 63;
  const int n = lane & 15, quad = lane >> 4;
  const int r0 = rb * 128 + wave * 32 + n, r1 = r0 + 16;
  const int b = rb >= 72;
  const size_t cbase = (size_t)b * NPIX;

  const bf16x8 bh00 = *(const bf16x8*)(nf_hi + (size_t)r0 * 64 + quad * 8);
  const bf16x8 bh01 = *(const bf16x8*)(nf_hi + (size_t)r0 * 64 + 32 + quad * 8);
  const bf16x8 bh10 = *(const bf16x8*)(nf_hi + (size_t)r1 * 64 + quad * 8);
  const bf16x8 bh11 = *(const bf16x8*)(nf_hi + (size_t)r1 * 64 + 32 + quad * 8);

  // staging map: chunk e = i*256+tid -> col e>>3, off (e&7)*8 ushorts
  const int scol[3] = {tid >> 3, (256 + tid) >> 3, (512 + tid) >> 3};
  const int soff = (tid & 7) * 8;
  uint4 rg[3];
  {
    const int cb = q * ECOLS;
#pragma unroll
    for (int i = 0; i < 3; ++i)
      rg[i] = *(const uint4*)(nf_hi + (cbase + cb + scol[i]) * 64 + soff);
  }

  float cm0 = -1e30f, cm1 = -1e30f;

  for (int t = 0; t < NTE; ++t) {
    __syncthreads();
#pragma unroll
    for (int i = 0; i < 3; ++i)
      *(uint4*)(sh + scol[i] * SST + soff) = rg[i];
    if (t + 1 < NTE) {
      const int cb = q * ECOLS + (t + 1) * CT;
#pragma unroll
      for (int i = 0; i < 3; ++i)
        rg[i] = *(const uint4*)(nf_hi + (cbase + cb + scol[i]) * 64 + soff);
    }
    __syncthreads();

#pragma unroll 2
    for (int st = 0; st < 6; ++st) {
      const ushort_t* ap = sh + (st * 16 + n) * SST + quad * 8;
      bf16x8 ah0 = *(const bf16x8*)ap;
      bf16x8 ah1 = *(const bf16x8*)(ap + 32);
      f32x4 z = {0.f, 0.f, 0.f, 0.f};
      f32x4 a0 = __builtin_amdgcn_mfma_f32_16x16x32_bf16(ah0, bh00, z, 0, 0, 0);
      a0 = __builtin_amdgcn_mfma_f32_16x16x32_bf16(ah1, bh01, a0, 0, 0, 0);
      f32x4 a1 = __builtin_amdgcn_mfma_f32_16x16x32_bf16(ah0, bh10, z, 0, 0, 0);
      a1 = __builtin_amdgcn_mfma_f32_16x16x32_bf16(ah1, bh11, a1, 0, 0, 0);
      cm0 = fmaxf(cm0, fmaxf(fmaxf(a0[0], a0[1]), fmaxf(a0[2], a0[3])));
      cm1 = fmaxf(cm1, fmaxf(fmaxf(a1[0], a1[1]), fmaxf(a1[2], a1[3])));
    }
    if (t == 2 || t == 5) {  // 3 tiles = 72 cols per (q,quad)-stream chunk
      const int cn = (q * 4 + quad) * 2 + (t / 3);
      tmax[(size_t)r0 * NCHK + cn] = cm0;
      tmax[(size_t)r1 * NCHK + cn] = cm1;
      cm0 = -1e30f; cm1 = -1e30f;
    }
  }
}

// ---------------- K2b: threshold = 16th largest of 128 chunk maxima - margin ----------------
__global__ __launch_bounds__(256) void k_thresh(
    const float* __restrict__ tmax, float* __restrict__ Tb) {
  const int wave = threadIdx.x >> 6, lane = threadIdx.x & 63;
  const int row = blockIdx.x * 4 + wave;
  const float* tp = tmax + (size_t)row * NCHK;
  float v0 = tp[lane];
  float v1 = tp[64 + lane];
  float m = -1e30f;
#pragma unroll
  for (int k = 0; k < TK; ++k) {
    float c = fmaxf(v0, v1);
#pragma unroll
    for (int d = 1; d < 64; d <<= 1) c = fmaxf(c, __shfl_xor(c, d));
    m = c;
    if (v0 == m) v0 = -1e30f;  // killing duplicates only lowers T: safe
    if (v1 == m) v1 = -1e30f;
  }
  if (lane == 0) Tb[row] = m - MARGIN;
}

// ---------------- K2c: pass B — hi sims again, append cols with s_hi >= T ----------------
__global__ __launch_bounds__(256) void k_collect(
    const ushort_t* __restrict__ nf_hi, const float* __restrict__ Tb,
    int* __restrict__ cidx, int* __restrict__ rowcnt) {
  __shared__ ushort_t sh[CT * SST];
  const int rb = blockIdx.x >> 4, q = blockIdx.x & 15;
  const int tid = threadIdx.x, wave = tid >> 6, lane = tid & 63;
  const int n = lane & 15, quad = lane >> 4;
  const int r0 = rb * 128 + wave * 32 + n, r1 = r0 + 16;
  const int b = rb >= 72;
  const size_t cbase = (size_t)b * NPIX;

  const bf16x8 bh00 = *(const bf16x8*)(nf_hi + (size_t)r0 * 64 + quad * 8);
  const bf16x8 bh01 = *(const bf16x8*)(nf_hi + (size_t)r0 * 64 + 32 + quad * 8);
  const bf16x8 bh10 = *(const bf16x8*)(nf_hi + (size_t)r1 * 64 + quad * 8);
  const bf16x8 bh11 = *(const bf16x8*)(nf_hi + (size_t)r1 * 64 + 32 + quad * 8);

  const float T0 = Tb[r0], T1 = Tb[r1];

  const int scol[3] = {tid >> 3, (256 + tid) >> 3, (512 + tid) >> 3};
  const int soff = (tid & 7) * 8;
  uint4 rg[3];
  {
    const int cb = q * ECOLS;
#pragma unroll
    for (int i = 0; i < 3; ++i)
      rg[i] = *(const uint4*)(nf_hi + (cbase + cb + scol[i]) * 64 + soff);
  }

  for (int t = 0; t < NTE; ++t) {
    const int cb = q * ECOLS + t * CT;
    __syncthreads();
#pragma unroll
    for (int i = 0; i < 3; ++i)
      *(uint4*)(sh + scol[i] * SST + soff) = rg[i];
    if (t + 1 < NTE) {
      const int cb1 = q * ECOLS + (t + 1) * CT;
#pragma unroll
      for (int i = 0; i < 3; ++i)
        rg[i] = *(const uint4*)(nf_hi + (cbase + cb1 + scol[i]) * 64 + soff);
    }
    __syncthreads();

#pragma unroll 2
    for (int st = 0; st < 6; ++st) {
      const ushort_t* ap = sh + (st * 16 + n) * SST + quad * 8;
      bf16x8 ah0 = *(const bf16x8*)ap;
      bf16x8 ah1 = *(const bf16x8*)(ap + 32);
      f32x4 z = {0.f, 0.f, 0.f, 0.f};
      f32x4 a0 = __builtin_amdgcn_mfma_f32_16x16x32_bf16(ah0, bh00, z, 0, 0, 0);
      a0 = __builtin_amdgcn_mfma_f32_16x16x32_bf16(ah1, bh01, a0, 0, 0, 0);
      f32x4 a1 = __builtin_amdgcn_mfma_f32_16x16x32_bf16(ah0, bh10, z, 0, 0, 0);
      a1 = __builtin_amdgcn_mfma_f32_16x16x32_bf16(ah1, bh11, a1, 0, 0, 0);

      const int c0 = cb + st * 16 + quad * 4;
      const float mx0 = fmaxf(fmaxf(a0[0], a0[1]), fmaxf(a0[2], a0[3]));
      if (mx0 >= T0) {
#pragma unroll
        for (int r = 0; r < 4; ++r)
          if (a0[r] >= T0) {
            const int slot = atomicAdd(rowcnt + r0, 1);
            if (slot < MAXC) cidx[(size_t)r0 * MAXC + slot] = c0 + r;
          }
      }
      const float mx1 = fmaxf(fmaxf(a1[0], a1[1]), fmaxf(a1[2], a1[3]));
      if (mx1 >= T1) {
#pragma unroll
        for (int r = 0; r < 4; ++r)
          if (a1[r] >= T1) {
            const int slot = atomicAdd(rowcnt + r1, 1);
            if (slot < MAXC) cidx[(size_t)r1 * MAXC + slot] = c0 + r;
          }
      }
    }
  }
}

// ---------------- K3: exact fp32 dots on candidates + top-16 + gather + mean ----------------
// wave per 4 rows; grid NROWS/16 = 1152
__global__ __launch_bounds__(256) void k_merge_gather(
    const float* __restrict__ nf, const int* __restrict__ cidx,
    const int* __restrict__ rowcnt, float* __restrict__ corr) {
  const int wave = threadIdx.x >> 6, lane = threadIdx.x & 63;
  const int row0 = blockIdx.x * 16 + wave * 4;
#pragma unroll 1
  for (int rr = 0; rr < 4; ++rr) {
    const int row = row0 + rr;
    const int b = row >= NPIX;
    const int rl = row - b * NPIX;
    const float* nfb = nf + (size_t)b * NPIX * RC;
    const int C = min(rowcnt[row], MAXC);

    float4 rv[16];
    const float4* r4 = (const float4*)(nf + (size_t)row * RC);
#pragma unroll
    for (int i = 0; i < 16; ++i) rv[i] = r4[i];  // broadcast loads

    const int* cp = cidx + (size_t)row * MAXC;
    unsigned long long k0 = 0, k1 = 0;
    {
      const int c0 = (lane < C) ? cp[lane] : rl;
      const float4* g = (const float4*)(nfb + (size_t)c0 * RC);
      float s = 0.f;
#pragma unroll
      for (int i = 0; i < 16; ++i) {
        float4 a = g[i];
        s += a.x * rv[i].x + a.y * rv[i].y + a.z * rv[i].z + a.w * rv[i].w;
      }
      if (lane < C)
        k0 = ((unsigned long long)ordu(s) << 32) | (uint_t)(~(uint_t)c0);
    }
    if (C > 64) {  // wave-uniform branch, rare
      const int c1 = (64 + lane < C) ? cp[64 + lane] : rl;
      const float4* g = (const float4*)(nfb + (size_t)c1 * RC);
      float s = 0.f;
#pragma unroll
      for (int i = 0; i < 16; ++i) {
        float4 a = g[i];
        s += a.x * rv[i].x + a.y * rv[i].y + a.z * rv[i].z + a.w * rv[i].w;
      }
      if (64 + lane < C)
        k1 = ((unsigned long long)ordu(s) << 32) | (uint_t)(~(uint_t)c1);
    }

    int sel[TK];
#pragma unroll
    for (int t = 0; t < TK; ++t) {
      unsigned long long m = k0 > k1 ? k0 : k1;
#pragma unroll
      for (int d = 1; d < 64; d <<= 1) {
        unsigned long long o = __shfl_xor(m, d);
        m = (o > m) ? o : m;
      }
      sel[t] = (m == 0) ? rl : (int)(~(uint_t)(m & 0xFFFFFFFFull));
      if (k0 == m) k0 = 0;
      else if (k1 == m) k1 = 0;
    }

    float acc = 0.f;
#pragma unroll
    for (int t = 0; t < TK; ++t)
      acc += nfb[(size_t)sel[t] * RC + lane];  // coalesced 256B per t
    corr[(size_t)row * RC + lane] = acc * 0.0625f;
  }
}

// ---------------- K4: proj back to C channels + residual add ----------------
// grid: 72 pixgroups x 8 channel-eighths = 576
__global__ __launch_bounds__(256) void k_proj_add(
    const float* __restrict__ x, const float* __restrict__ wp,
    const float* __restrict__ corr, float* __restrict__ out) {
  const int pg = blockIdx.x >> 3, cq = blockIdx.x & 7;
  const int tid = threadIdx.x;

  __shared__ float wl[32 * RC];  // 8 KB
  {
    const float4* src = (const float4*)(wp + (size_t)cq * 32 * RC);
    float4* dst = (float4*)wl;
#pragma unroll
    for (int i = 0; i < 2; ++i) dst[i * 256 + tid] = src[i * 256 + tid];
  }

  const int p = pg * 256 + tid;
  const int b = p >= NPIX;
  const int n = p - b * NPIX;

  float4 cr[16];
  const float4* c4 = (const float4*)(corr + (size_t)p * RC);
#pragma unroll
  for (int i = 0; i < 16; ++i) cr[i] = c4[i];
  __syncthreads();

  const size_t xb = (size_t)b * NC * NPIX + n;
  for (int cl = 0; cl < 32; ++cl) {
    const float4* w4 = (const float4*)(wl + cl * RC);  // broadcast
    float s = 0.f;
#pragma unroll
    for (int i = 0; i < 16; ++i) {
      float4 w = w4[i];
      s += w.x * cr[i].x + w.y * cr[i].y + w.z * cr[i].z + w.w * cr[i].w;
    }
    const int c = cq * 32 + cl;
    const size_t oi = xb + (size_t)c * NPIX;
    out[oi] = x[oi] + s;  // coalesced
  }
}

extern "C" void kernel_launch(void* const* d_in, const int* in_sizes, int n_in,
                              void* d_out, int out_size, void* d_ws, size_t ws_size,
                              hipStream_t stream) {
  const float* x = (const float*)d_in[0];
  const float* wr = (const float*)d_in[1];
  const float* wp = (const float*)d_in[2];
  float* out = (float*)d_out;

  char* ws = (char*)d_ws;
  // region1 (18,874,368 B) time-shares: feat4 (reduce->normsplit),
  // tmax (sim_max->thresh, 9.4 MB), corr (merge->proj) — lifetimes disjoint.
  float* feat4 = (float*)ws;
  float* tmax = (float*)ws;
  float* corr = (float*)ws;
  float* nf = (float*)(ws + 18874368);
  ushort_t* nf_hi = (ushort_t*)(ws + 23592960);
  float* Tb = (float*)(ws + 25952256);
  int* rowcnt = (int*)(ws + 26025984);
  int* cidx = (int*)(ws + 26099712);
  // total 35,536,896 B

  hipLaunchKernelGGL(k_reduce, dim3(576), dim3(256), 0, stream, x, wr, feat4);
  hipLaunchKernelGGL(k_normsplit, dim3(288), dim3(256), 0, stream, feat4, nf, nf_hi);
  hipLaunchKernelGGL(k_sim_max, dim3(2304), dim3(256), 0, stream, nf_hi, tmax);
  hipLaunchKernelGGL(k_thresh, dim3(NROWS / 4), dim3(256), 0, stream, tmax, Tb);
  hipMemsetAsync(rowcnt, 0, NROWS * sizeof(int), stream);
  hipLaunchKernelGGL(k_collect, dim3(2304), dim3(256), 0, stream,
                     nf_hi, Tb, cidx, rowcnt);
  hipLaunchKernelGGL(k_merge_gather, dim3(1152), dim3(256), 0, stream,
                     nf, cidx, rowcnt, corr);
  hipLaunchKernelGGL(k_proj_add, dim3(576), dim3(256), 0, stream, x, wp, corr, out);
}